// Round 2
// baseline (32213.223 us; speedup 1.0000x reference)
//
#include <hip/hip_runtime.h>
#include <math.h>

#define NEGV (-100000.0f)
constexpr int Bn = 64, Sn = 512, En = 256, Hn = 256, HIDn = 512, Tn = 9;
constexpr int START_T = Tn - 2, STOP_T = Tn - 1;
constexpr int G4 = 4 * Hn; // 1024 gate rows

__device__ __forceinline__ float sigf(float x) { return 1.0f / (1.0f + __expf(-x)); }
__device__ __forceinline__ float tanh_f(float x) { return 2.0f / (1.0f + __expf(-2.0f * x)) - 1.0f; }

// ---------------- prep: transpose weights to [dir][k][1024], combine biases ----------------
__global__ void prep_kernel(const float* __restrict__ wih0, const float* __restrict__ whh0,
                            const float* __restrict__ bih0, const float* __restrict__ bhh0,
                            const float* __restrict__ wih1, const float* __restrict__ whh1,
                            const float* __restrict__ bih1, const float* __restrict__ bhh1,
                            float* wih0t, float* whh0t, float* wih1t, float* whh1t,
                            float* bias0, float* bias1) {
  int tid = blockIdx.x * blockDim.x + threadIdx.x;
  int nth = gridDim.x * blockDim.x;
  for (int idx = tid; idx < 2 * G4 * En; idx += nth) {
    int d = idx / (G4 * En); int rem = idx % (G4 * En); int r = rem / En; int e = rem % En;
    wih0t[(d * En + e) * G4 + r] = wih0[idx];
  }
  for (int idx = tid; idx < 2 * G4 * Hn; idx += nth) {
    int d = idx / (G4 * Hn); int rem = idx % (G4 * Hn); int r = rem / Hn; int e = rem % Hn;
    whh0t[(d * Hn + e) * G4 + r] = whh0[idx];
  }
  for (int idx = tid; idx < 2 * G4 * HIDn; idx += nth) {
    int d = idx / (G4 * HIDn); int rem = idx % (G4 * HIDn); int r = rem / HIDn; int e = rem % HIDn;
    wih1t[(d * HIDn + e) * G4 + r] = wih1[idx];
  }
  for (int idx = tid; idx < 2 * G4 * Hn; idx += nth) {
    int d = idx / (G4 * Hn); int rem = idx % (G4 * Hn); int r = rem / Hn; int e = rem % Hn;
    whh1t[(d * Hn + e) * G4 + r] = whh1[idx];
  }
  for (int idx = tid; idx < 2 * G4; idx += nth) {
    bias0[idx] = bih0[idx] + bhh0[idx];
    bias1[idx] = bih1[idx] + bhh1[idx];
  }
}

// ---------------- persistent LSTM: one WG per (dir, batch-pair); 2 syncthreads/step ----------------
template <int EIN>
__global__ __launch_bounds__(256) void lstm_kernel(
    const float* __restrict__ wih_t,  // [2][EIN][1024] transposed
    const float* __restrict__ whh_t,  // [2][256][1024] transposed
    const float* __restrict__ bias,   // [2][1024] combined
    const float* __restrict__ xsrc,   // emb (layer0) or out0 (layer1)
    const int* __restrict__ sent,     // layer0 only
    float* __restrict__ out)          // [B][S][512]; fwd->cols 0:256, bwd->256:512
{
  __shared__ float2 xb[EIN];      // interleaved {batch0, batch1}
  __shared__ float2 hb[Hn];
  __shared__ float4 gb[2][Hn];    // gate pre-acts; flat float index == gate row

  const int j = threadIdx.x;          // 0..255
  const int wg = blockIdx.x;          // 0..63
  const int dir = wg >> 5;            // 0 fwd, 1 bwd
  const int pair = wg & 31;
  const int b0 = pair * 2;

  const float* Wx = wih_t + dir * EIN * G4;
  const float* Wh = whh_t + dir * Hn * G4;
  const float bi = bias[dir * G4 + j];
  const float bf = bias[dir * G4 + Hn + j];
  const float bg = bias[dir * G4 + 2 * Hn + j];
  const float bo = bias[dir * G4 + 3 * Hn + j];

  float c0 = 0.0f, c1 = 0.0f;
  hb[j] = make_float2(0.0f, 0.0f);
  __syncthreads();

  const float4* wxp = reinterpret_cast<const float4*>(Wx) + j; // stride G4/4 per k
  const float4* whp = reinterpret_cast<const float4*>(Wh) + j;

  for (int s = 0; s < Sn; ++s) {
    const int t = dir ? (Sn - 1 - s) : s;

    // stage x_t for both batches
    if (EIN == En) {
      int s0 = sent[b0 * Sn + t];
      int s1 = sent[(b0 + 1) * Sn + t];
      xb[j] = make_float2(xsrc[s0 * En + j], xsrc[s1 * En + j]);
    } else {
      const float* r0 = xsrc + (b0 * Sn + t) * HIDn;
      const float* r1 = xsrc + ((b0 + 1) * Sn + t) * HIDn;
      xb[j] = make_float2(r0[j], r1[j]);
      xb[Hn + j] = make_float2(r0[Hn + j], r1[Hn + j]);
    }
    __syncthreads();

    // phase A: thread j accumulates gate rows 4j..4j+3 for both batches
    float4 a0 = make_float4(0.f, 0.f, 0.f, 0.f);
    float4 a1 = make_float4(0.f, 0.f, 0.f, 0.f);
#pragma unroll 8
    for (int k = 0; k < EIN; ++k) {
      float4 w = wxp[k * (G4 / 4)];
      float2 x = xb[k];
      a0.x += w.x * x.x; a0.y += w.y * x.x; a0.z += w.z * x.x; a0.w += w.w * x.x;
      a1.x += w.x * x.y; a1.y += w.y * x.y; a1.z += w.z * x.y; a1.w += w.w * x.y;
    }
#pragma unroll 8
    for (int k = 0; k < Hn; ++k) {
      float4 w = whp[k * (G4 / 4)];
      float2 h = hb[k];
      a0.x += w.x * h.x; a0.y += w.y * h.x; a0.z += w.z * h.x; a0.w += w.w * h.x;
      a1.x += w.x * h.y; a1.y += w.y * h.y; a1.z += w.z * h.y; a1.w += w.w * h.y;
    }
    gb[0][j] = a0;
    gb[1][j] = a1;
    __syncthreads();

    // phase C: thread j owns hidden unit j (rows j, 256+j, 512+j, 768+j)
    {
      const float* g0 = reinterpret_cast<const float*>(&gb[0][0]);
      const float* g1 = reinterpret_cast<const float*>(&gb[1][0]);
      float i0 = g0[j] + bi, f0 = g0[Hn + j] + bf, gg0 = g0[2 * Hn + j] + bg, o0 = g0[3 * Hn + j] + bo;
      c0 = sigf(f0) * c0 + sigf(i0) * tanh_f(gg0);
      float h0 = sigf(o0) * tanh_f(c0);
      float i1 = g1[j] + bi, f1 = g1[Hn + j] + bf, gg1 = g1[2 * Hn + j] + bg, o1 = g1[3 * Hn + j] + bo;
      c1 = sigf(f1) * c1 + sigf(i1) * tanh_f(gg1);
      float h1 = sigf(o1) * tanh_f(c1);
      hb[j] = make_float2(h0, h1);
      out[(b0 * Sn + t) * HIDn + dir * Hn + j] = h0;
      out[((b0 + 1) * Sn + t) * HIDn + dir * Hn + j] = h1;
    }
    __syncthreads();
  }
}

// ---------------- FC: one wave per (b,t) ----------------
__global__ __launch_bounds__(64) void fc_kernel(const float* __restrict__ out1,
                                                const float* __restrict__ fcw,
                                                const float* __restrict__ fcb,
                                                float* __restrict__ feats) {
  const int bs = blockIdx.x;  // 0..B*S-1
  const int l = threadIdx.x;  // 0..63
  const float* row = out1 + bs * HIDn;
  float v[8];
#pragma unroll
  for (int i = 0; i < 8; ++i) v[i] = row[l + 64 * i];
#pragma unroll
  for (int tag = 0; tag < Tn; ++tag) {
    const float* w = fcw + tag * HIDn;
    float acc = 0.0f;
#pragma unroll
    for (int i = 0; i < 8; ++i) acc += v[i] * w[l + 64 * i];
#pragma unroll
    for (int off = 32; off; off >>= 1) acc += __shfl_xor(acc, off);
    if (l == 0) feats[bs * Tn + tag] = acc + fcb[tag];
  }
}

// ---------------- CRF forward + gold, one wave per batch ----------------
__global__ __launch_bounds__(64) void crf_kernel(const float* __restrict__ feats,
                                                 const int* __restrict__ tags,
                                                 const int* __restrict__ lens,
                                                 const float* __restrict__ trans,
                                                 float* __restrict__ scores) {
  const int b = blockIdx.x;
  const int j = threadIdx.x;          // lanes 0..8 hold alpha, all 64 participate in shfl
  const int jj = j < Tn ? j : Tn - 1;
  const int len = lens[b];

  float trc[Tn];
#pragma unroll
  for (int i = 0; i < Tn; ++i) trc[i] = trans[i * Tn + jj];
  const float trS = trans[jj * Tn + STOP_T];

  float alpha = (j == START_T) ? 0.0f : NEGV;
  const float* fb = feats + b * Sn * Tn;

  for (int t = 0; t < Sn; ++t) {
    float f = (j < Tn) ? fb[t * Tn + j] : 0.0f;
    float v[Tn];
    float m = -3.0e38f;
#pragma unroll
    for (int i = 0; i < Tn; ++i) {
      float ai = __shfl(alpha, i);
      v[i] = ai + trc[i];
      m = fmaxf(m, v[i]);
    }
    float ssum = 0.0f;
#pragma unroll
    for (int i = 0; i < Tn; ++i) ssum += __expf(v[i] - m);
    float newa = m + __logf(ssum) + f;
    if (t < len && j < Tn) alpha = newa;
  }

  float val = (j < Tn) ? alpha + trS : -3.0e38f;
  float m = val;
#pragma unroll
  for (int off = 32; off; off >>= 1) m = fmaxf(m, __shfl_xor(m, off));
  float se = (j < Tn) ? __expf(val - m) : 0.0f;
#pragma unroll
  for (int off = 32; off; off >>= 1) se += __shfl_xor(se, off);
  float fscore = m + __logf(se);

  // gold score: lane l sums pair terms for s = 8l .. 8l+7 (s < 511)
  const int* tg = tags + b * Sn;
  float part = 0.0f;
  for (int q = 0; q < 8; ++q) {
    int s0 = j * 8 + q;
    if (s0 < Sn - 1 && (s0 + 1) < len) {
      int ta = tg[s0], tb = tg[s0 + 1];
      part += trans[ta * Tn + tb] + fb[s0 * Tn + tb];
    }
  }
#pragma unroll
  for (int off = 32; off; off >>= 1) part += __shfl_xor(part, off);

  if (j == 0) {
    int t0 = tg[0];
    int tl = tg[len - 1];
    float gold = trans[START_T * Tn + t0] + fb[0 * Tn + t0] + part + trans[tl * Tn + STOP_T];
    scores[b] = fscore - gold;
  }
}

__global__ void finalize_kernel(const float* __restrict__ scores, float* __restrict__ out) {
  int l = threadIdx.x;
  float v = scores[l];
#pragma unroll
  for (int off = 32; off; off >>= 1) v += __shfl_xor(v, off);
  if (l == 0) out[0] = v / 64.0f;
}

extern "C" void kernel_launch(void* const* d_in, const int* in_sizes, int n_in,
                              void* d_out, int out_size, void* d_ws, size_t ws_size,
                              hipStream_t stream) {
  const int* sent = (const int*)d_in[0];
  const int* tags = (const int*)d_in[1];
  const int* lens = (const int*)d_in[2];
  const float* emb = (const float*)d_in[3];
  const float* wih0 = (const float*)d_in[4];
  const float* whh0 = (const float*)d_in[5];
  const float* bih0 = (const float*)d_in[6];
  const float* bhh0 = (const float*)d_in[7];
  const float* wih1 = (const float*)d_in[8];
  const float* whh1 = (const float*)d_in[9];
  const float* bih1 = (const float*)d_in[10];
  const float* bhh1 = (const float*)d_in[11];
  const float* fcw = (const float*)d_in[12];
  const float* fcb = (const float*)d_in[13];
  const float* trans = (const float*)d_in[14];

  float* ws = (float*)d_ws;
  float* out0 = ws;                       // 64*512*512
  float* out1 = out0 + (size_t)Bn * Sn * HIDn;
  float* feats = out1 + (size_t)Bn * Sn * HIDn;   // B*S*T
  float* scores = feats + (size_t)Bn * Sn * Tn;   // 64
  float* wih0t = scores + 64;             // 2*256*1024
  float* whh0t = wih0t + 2 * En * G4;     // 2*256*1024
  float* wih1t = whh0t + 2 * Hn * G4;     // 2*512*1024
  float* whh1t = wih1t + 2 * HIDn * G4;   // 2*256*1024
  float* bias0 = whh1t + 2 * Hn * G4;     // 2*1024
  float* bias1 = bias0 + 2 * G4;          // 2*1024

  prep_kernel<<<1024, 256, 0, stream>>>(wih0, whh0, bih0, bhh0, wih1, whh1, bih1, bhh1,
                                        wih0t, whh0t, wih1t, whh1t, bias0, bias1);

  lstm_kernel<En><<<64, 256, 0, stream>>>(wih0t, whh0t, bias0, emb, sent, out0);
  lstm_kernel<HIDn><<<64, 256, 0, stream>>>(wih1t, whh1t, bias1, out0, nullptr, out1);

  fc_kernel<<<Bn * Sn, 64, 0, stream>>>(out1, fcw, fcb, feats);
  crf_kernel<<<Bn, 64, 0, stream>>>(feats, tags, lens, trans, scores);
  finalize_kernel<<<1, 64, 0, stream>>>(scores, (float*)d_out);
}

// Round 4
// 9992.364 us; speedup vs baseline: 3.2238x; 3.2238x over previous
//
#include <hip/hip_runtime.h>
#include <math.h>

#define NEGV (-100000.0f)
constexpr int Bn = 64, Sn = 512, En = 256, Hn = 256, HIDn = 512, Tn = 9;
constexpr int START_T = Tn - 2, STOP_T = Tn - 1;
constexpr int Mn = Bn * Sn; // 32768 rows

typedef unsigned int u32;
typedef unsigned short u16;

__device__ __forceinline__ float sigf(float x) { return 1.0f / (1.0f + __expf(-x)); }
__device__ __forceinline__ float tanh_f(float x) { return 2.0f / (1.0f + __expf(-2.0f * x)) - 1.0f; }
__device__ __forceinline__ u16 f2bf(float f) {
  u32 u = __float_as_uint(f);
  return (u16)((u + 0x7fffu + ((u >> 16) & 1u)) >> 16);
}
__device__ __forceinline__ float bflo(u32 u) { return __uint_as_float(u << 16); }
__device__ __forceinline__ float bfhi(u32 u) { return __uint_as_float(u & 0xffff0000u); }

// ---------------- prep: bf16 weight transposes/packs + combined biases ----------------
__global__ void prep_kernel(const float* __restrict__ wih0, const float* __restrict__ whh0,
                            const float* __restrict__ bih0, const float* __restrict__ bhh0,
                            const float* __restrict__ wih1, const float* __restrict__ whh1,
                            const float* __restrict__ bih1, const float* __restrict__ bhh1,
                            u16* __restrict__ wih0t, u16* __restrict__ wih1t,
                            u32* __restrict__ whh2_0, u32* __restrict__ whh2_1,
                            float* __restrict__ bias0, float* __restrict__ bias1) {
  int tid = blockIdx.x * blockDim.x + threadIdx.x;
  int nth = gridDim.x * blockDim.x;
  // wih0t[(d*256+e)*1024 + r] = bf16(wih0[(d*1024+r)*256 + e])
  for (int idx = tid; idx < 2 * 256 * 1024; idx += nth) {
    int d = idx >> 18, rem = idx & 262143, e = rem >> 10, r = rem & 1023;
    wih0t[idx] = f2bf(wih0[(d * 1024 + r) * 256 + e]);
  }
  // wih1t[(d*512+e)*1024 + r] = bf16(wih1[(d*1024+r)*512 + e])
  for (int idx = tid; idx < 2 * 512 * 1024; idx += nth) {
    int d = idx >> 19, rem = idx & 524287, e = rem >> 10, r = rem & 1023;
    wih1t[idx] = f2bf(wih1[(d * 1024 + r) * 512 + e]);
  }
  // whh2[d][k2][r] packs whh[d][r][2k2] (lo) and whh[d][r][2k2+1] (hi)
  for (int idx = tid; idx < 2 * 128 * 1024; idx += nth) {
    int d = idx >> 17, rem = idx & 131071, k2 = rem >> 10, r = rem & 1023;
    int base = (d * 1024 + r) * 256 + 2 * k2;
    whh2_0[idx] = (u32)f2bf(whh0[base]) | ((u32)f2bf(whh0[base + 1]) << 16);
    whh2_1[idx] = (u32)f2bf(whh1[base]) | ((u32)f2bf(whh1[base + 1]) << 16);
  }
  for (int idx = tid; idx < 2 * 1024; idx += nth) {
    bias0[idx] = bih0[idx] + bhh0[idx];
    bias1[idx] = bih1[idx] + bhh1[idx];
  }
}

// ---------------- input-projection GEMM: gx[dir][m][1024] = X[m] @ Wt[dir] + bias ----------------
// GATHER: xsrc = fp32 emb rows via sent[m].  !GATHER: xsrc = bf16 dense [M][K].
template <int K, bool GATHER>
__global__ __launch_bounds__(256) void gemm_gx(
    const void* __restrict__ xsrc_v,
    const int* __restrict__ sent,
    const u16* __restrict__ wt,       // [2][K][1024] bf16
    const float* __restrict__ bias,   // [2][1024]
    u16* __restrict__ gx)             // [2*M][1024] bf16
{
  constexpr int BM = 64, BN = 64, BK = 32;
  __shared__ float Xs[BK][BM];
  __shared__ float Ws[BK][BN];
  const int tid = threadIdx.x;
  const int tx = tid & 15, ty = tid >> 4;
  const int n0 = blockIdx.x * BN;
  const int m0 = blockIdx.y * BM;
  const int dir = blockIdx.z;

  const int lrow = tid >> 3;        // 0..31
  const int lk = (tid & 7) * 4;     // X k offset
  const int wk = tid >> 3;          // W k row
  const int wn = (tid & 7) * 8;     // W n offset

  float acc[4][4] = {};

  for (int k0 = 0; k0 < K; k0 += BK) {
#pragma unroll
    for (int rr = 0; rr < 2; ++rr) {
      int m = m0 + lrow + rr * 32;
      if constexpr (GATHER) {
        const float* xrow = (const float*)xsrc_v + (size_t)sent[m] * K;
        float4 v = *reinterpret_cast<const float4*>(xrow + k0 + lk);
        Xs[lk + 0][lrow + rr * 32] = v.x;
        Xs[lk + 1][lrow + rr * 32] = v.y;
        Xs[lk + 2][lrow + rr * 32] = v.z;
        Xs[lk + 3][lrow + rr * 32] = v.w;
      } else {
        const u16* xrow = (const u16*)xsrc_v + (size_t)m * K;
        uint2 v = *reinterpret_cast<const uint2*>(xrow + k0 + lk);
        Xs[lk + 0][lrow + rr * 32] = bflo(v.x);
        Xs[lk + 1][lrow + rr * 32] = bfhi(v.x);
        Xs[lk + 2][lrow + rr * 32] = bflo(v.y);
        Xs[lk + 3][lrow + rr * 32] = bfhi(v.y);
      }
    }
    {
      const u16* wp = wt + ((size_t)dir * K + k0 + wk) * 1024 + n0 + wn;
      uint4 wv = *reinterpret_cast<const uint4*>(wp);
      Ws[wk][wn + 0] = bflo(wv.x); Ws[wk][wn + 1] = bfhi(wv.x);
      Ws[wk][wn + 2] = bflo(wv.y); Ws[wk][wn + 3] = bfhi(wv.y);
      Ws[wk][wn + 4] = bflo(wv.z); Ws[wk][wn + 5] = bfhi(wv.z);
      Ws[wk][wn + 6] = bflo(wv.w); Ws[wk][wn + 7] = bfhi(wv.w);
    }
    __syncthreads();
#pragma unroll 8
    for (int k = 0; k < BK; ++k) {
      float4 a = *reinterpret_cast<const float4*>(&Xs[k][ty * 4]);
      float4 b = *reinterpret_cast<const float4*>(&Ws[k][tx * 4]);
      acc[0][0] += a.x * b.x; acc[0][1] += a.x * b.y; acc[0][2] += a.x * b.z; acc[0][3] += a.x * b.w;
      acc[1][0] += a.y * b.x; acc[1][1] += a.y * b.y; acc[1][2] += a.y * b.z; acc[1][3] += a.y * b.w;
      acc[2][0] += a.z * b.x; acc[2][1] += a.z * b.y; acc[2][2] += a.z * b.z; acc[2][3] += a.z * b.w;
      acc[3][0] += a.w * b.x; acc[3][1] += a.w * b.y; acc[3][2] += a.w * b.z; acc[3][3] += a.w * b.w;
    }
    __syncthreads();
  }

  float4 bv = *reinterpret_cast<const float4*>(&bias[dir * 1024 + n0 + tx * 4]);
#pragma unroll
  for (int i = 0; i < 4; ++i) {
    int m = m0 + ty * 4 + i;
    ushort4 sv;
    sv.x = f2bf(acc[i][0] + bv.x);
    sv.y = f2bf(acc[i][1] + bv.y);
    sv.z = f2bf(acc[i][2] + bv.z);
    sv.w = f2bf(acc[i][3] + bv.w);
    *reinterpret_cast<ushort4*>(gx + ((size_t)dir * Mn + m) * 1024 + n0 + tx * 4) = sv;
  }
}

// ---------------- sequential recurrence: h @ Whh only; gx holds x-part + bias ----------------
__global__ __launch_bounds__(256) void lstm_recur(
    const uint4* __restrict__ whh2,   // [2][128][256] uint4 (bf16 pairs, rows fastest)
    const u16* __restrict__ gx,       // [2*M][1024] bf16
    u16* __restrict__ out)            // [B][S][512] bf16; fwd->cols 0:256, bwd->256:512
{
  __shared__ float2 hb[Hn];
  __shared__ float4 gb[2][Hn];
  const int j = threadIdx.x;
  const int dir = blockIdx.x >> 5;
  const int b0 = (blockIdx.x & 31) * 2;

  float c0 = 0.0f, c1 = 0.0f;
  hb[j] = make_float2(0.0f, 0.0f);
  __syncthreads();

  const uint4* wp = whh2 + (size_t)dir * 128 * 256 + j;

  for (int s = 0; s < Sn; ++s) {
    const int t = dir ? (Sn - 1 - s) : s;
    const u16* g0p = gx + ((size_t)(dir * Mn + b0 * Sn + t)) * 1024 + 4 * j;
    uint2 gu0 = *reinterpret_cast<const uint2*>(g0p);
    uint2 gu1 = *reinterpret_cast<const uint2*>(g0p + (size_t)Sn * 1024);
    float4 a0 = make_float4(bflo(gu0.x), bfhi(gu0.x), bflo(gu0.y), bfhi(gu0.y));
    float4 a1 = make_float4(bflo(gu1.x), bfhi(gu1.x), bflo(gu1.y), bfhi(gu1.y));

#pragma unroll 8
    for (int k2 = 0; k2 < 128; ++k2) {
      uint4 w = wp[k2 * 256];
      float2 he = hb[2 * k2];
      float2 ho = hb[2 * k2 + 1];
      float wl, wh;
      wl = bflo(w.x); wh = bfhi(w.x);
      a0.x += wl * he.x + wh * ho.x; a1.x += wl * he.y + wh * ho.y;
      wl = bflo(w.y); wh = bfhi(w.y);
      a0.y += wl * he.x + wh * ho.x; a1.y += wl * he.y + wh * ho.y;
      wl = bflo(w.z); wh = bfhi(w.z);
      a0.z += wl * he.x + wh * ho.x; a1.z += wl * he.y + wh * ho.y;
      wl = bflo(w.w); wh = bfhi(w.w);
      a0.w += wl * he.x + wh * ho.x; a1.w += wl * he.y + wh * ho.y;
    }
    gb[0][j] = a0;
    gb[1][j] = a1;
    __syncthreads();

    {
      const float* g0 = reinterpret_cast<const float*>(&gb[0][0]);
      const float* g1 = reinterpret_cast<const float*>(&gb[1][0]);
      float i0 = g0[j], f0 = g0[Hn + j], gg0 = g0[2 * Hn + j], o0 = g0[3 * Hn + j];
      c0 = sigf(f0) * c0 + sigf(i0) * tanh_f(gg0);
      float h0 = sigf(o0) * tanh_f(c0);
      float i1 = g1[j], f1 = g1[Hn + j], gg1 = g1[2 * Hn + j], o1 = g1[3 * Hn + j];
      c1 = sigf(f1) * c1 + sigf(i1) * tanh_f(gg1);
      float h1 = sigf(o1) * tanh_f(c1);
      hb[j] = make_float2(h0, h1);
      out[(size_t)(b0 * Sn + t) * HIDn + dir * Hn + j] = f2bf(h0);
      out[(size_t)((b0 + 1) * Sn + t) * HIDn + dir * Hn + j] = f2bf(h1);
    }
    __syncthreads();
  }
}

// ---------------- FC: one wave per (b,t), bf16 input rows ----------------
__global__ __launch_bounds__(64) void fc_kernel(const u16* __restrict__ out1,
                                                const float* __restrict__ fcw,
                                                const float* __restrict__ fcb,
                                                float* __restrict__ feats) {
  const int bs = blockIdx.x;
  const int l = threadIdx.x;
  const u16* row = out1 + (size_t)bs * HIDn;
  uint4 rv = *reinterpret_cast<const uint4*>(row + l * 8);
  float v[8];
  v[0] = bflo(rv.x); v[1] = bfhi(rv.x);
  v[2] = bflo(rv.y); v[3] = bfhi(rv.y);
  v[4] = bflo(rv.z); v[5] = bfhi(rv.z);
  v[6] = bflo(rv.w); v[7] = bfhi(rv.w);
#pragma unroll
  for (int tag = 0; tag < Tn; ++tag) {
    const float* w = fcw + tag * HIDn + l * 8;
    float4 w0 = *reinterpret_cast<const float4*>(w);
    float4 w1 = *reinterpret_cast<const float4*>(w + 4);
    float acc = v[0] * w0.x + v[1] * w0.y + v[2] * w0.z + v[3] * w0.w
              + v[4] * w1.x + v[5] * w1.y + v[6] * w1.z + v[7] * w1.w;
#pragma unroll
    for (int off = 32; off; off >>= 1) acc += __shfl_xor(acc, off);
    if (l == 0) feats[bs * Tn + tag] = acc + fcb[tag];
  }
}

// ---------------- CRF forward + gold, one wave per batch ----------------
__global__ __launch_bounds__(64) void crf_kernel(const float* __restrict__ feats,
                                                 const int* __restrict__ tags,
                                                 const int* __restrict__ lens,
                                                 const float* __restrict__ trans,
                                                 float* __restrict__ scores) {
  const int b = blockIdx.x;
  const int j = threadIdx.x;
  const int jj = j < Tn ? j : Tn - 1;
  const int len = lens[b];

  float trc[Tn];
#pragma unroll
  for (int i = 0; i < Tn; ++i) trc[i] = trans[i * Tn + jj];
  const float trS = trans[jj * Tn + STOP_T];

  float alpha = (j == START_T) ? 0.0f : NEGV;
  const float* fb = feats + (size_t)b * Sn * Tn;

  for (int t = 0; t < Sn; ++t) {
    float f = (j < Tn) ? fb[t * Tn + j] : 0.0f;
    float v[Tn];
    float m = -3.0e38f;
#pragma unroll
    for (int i = 0; i < Tn; ++i) {
      float ai = __shfl(alpha, i);
      v[i] = ai + trc[i];
      m = fmaxf(m, v[i]);
    }
    float ssum = 0.0f;
#pragma unroll
    for (int i = 0; i < Tn; ++i) ssum += __expf(v[i] - m);
    float newa = m + __logf(ssum) + f;
    if (t < len && j < Tn) alpha = newa;
  }

  float val = (j < Tn) ? alpha + trS : -3.0e38f;
  float m = val;
#pragma unroll
  for (int off = 32; off; off >>= 1) m = fmaxf(m, __shfl_xor(m, off));
  float se = (j < Tn) ? __expf(val - m) : 0.0f;
#pragma unroll
  for (int off = 32; off; off >>= 1) se += __shfl_xor(se, off);
  float fscore = m + __logf(se);

  const int* tg = tags + b * Sn;
  float part = 0.0f;
  for (int q = 0; q < 8; ++q) {
    int s0 = j * 8 + q;
    if (s0 < Sn - 1 && (s0 + 1) < len) {
      int ta = tg[s0], tb = tg[s0 + 1];
      part += trans[ta * Tn + tb] + fb[s0 * Tn + tb];
    }
  }
#pragma unroll
  for (int off = 32; off; off >>= 1) part += __shfl_xor(part, off);

  if (j == 0) {
    int t0 = tg[0];
    int tl = tg[len - 1];
    float gold = trans[START_T * Tn + t0] + fb[0 * Tn + t0] + part + trans[tl * Tn + STOP_T];
    scores[b] = fscore - gold;
  }
}

__global__ void finalize_kernel(const float* __restrict__ scores, float* __restrict__ out) {
  int l = threadIdx.x;
  float v = scores[l];
#pragma unroll
  for (int off = 32; off; off >>= 1) v += __shfl_xor(v, off);
  if (l == 0) out[0] = v / 64.0f;
}

extern "C" void kernel_launch(void* const* d_in, const int* in_sizes, int n_in,
                              void* d_out, int out_size, void* d_ws, size_t ws_size,
                              hipStream_t stream) {
  const int* sent = (const int*)d_in[0];
  const int* tags = (const int*)d_in[1];
  const int* lens = (const int*)d_in[2];
  const float* emb = (const float*)d_in[3];
  const float* wih0 = (const float*)d_in[4];
  const float* whh0 = (const float*)d_in[5];
  const float* bih0 = (const float*)d_in[6];
  const float* bhh0 = (const float*)d_in[7];
  const float* wih1 = (const float*)d_in[8];
  const float* whh1 = (const float*)d_in[9];
  const float* bih1 = (const float*)d_in[10];
  const float* bhh1 = (const float*)d_in[11];
  const float* fcw = (const float*)d_in[12];
  const float* fcb = (const float*)d_in[13];
  const float* trans = (const float*)d_in[14];

  // workspace layout (~166 MB total; bf16 out buffer shared by layer0/layer1)
  char* ws = (char*)d_ws;
  u16* outb = (u16*)ws;                                  // Mn*512 bf16 = 33,554,432 B
  u16* gx = (u16*)(ws + 33554432);                       // 2*Mn*1024 bf16 = 134,217,728 B
  float* feats = (float*)(ws + 33554432 + 134217728);    // Mn*9 fp32
  float* scores = feats + (size_t)Mn * Tn;               // 64
  float* bias0 = scores + 64;                            // 2048
  float* bias1 = bias0 + 2048;                           // 2048
  u16* wih0t = (u16*)(bias1 + 2048);                     // 524,288 u16
  u16* wih1t = wih0t + 2 * 256 * 1024;                   // 1,048,576 u16
  u32* whh2_0 = (u32*)(wih1t + 2 * 512 * 1024);          // 262,144 u32
  u32* whh2_1 = whh2_0 + 2 * 128 * 1024;                 // 262,144 u32

  prep_kernel<<<2048, 256, 0, stream>>>(wih0, whh0, bih0, bhh0, wih1, whh1, bih1, bhh1,
                                        wih0t, wih1t, whh2_0, whh2_1, bias0, bias1);

  dim3 ggrid(1024 / 64, Mn / 64, 2);
  gemm_gx<256, true><<<ggrid, 256, 0, stream>>>(emb, sent, wih0t, bias0, gx);
  lstm_recur<<<64, 256, 0, stream>>>((const uint4*)whh2_0, gx, outb);
  gemm_gx<512, false><<<ggrid, 256, 0, stream>>>(outb, nullptr, wih1t, bias1, gx);
  lstm_recur<<<64, 256, 0, stream>>>((const uint4*)whh2_1, gx, outb);

  fc_kernel<<<Mn, 64, 0, stream>>>(outb, fcw, fcb, feats);
  crf_kernel<<<Bn, 64, 0, stream>>>(feats, tags, lens, trans, scores);
  finalize_kernel<<<1, 64, 0, stream>>>(scores, (float*)d_out);
}

// Round 5
// 6234.043 us; speedup vs baseline: 5.1673x; 1.6029x over previous
//
#include <hip/hip_runtime.h>
#include <math.h>

#define NEGV (-100000.0f)
constexpr int Bn = 64, Sn = 512, En = 256, Hn = 256, HIDn = 512, Tn = 9;
constexpr int START_T = Tn - 2, STOP_T = Tn - 1;
constexpr int Mn = Bn * Sn; // 32768 rows

typedef unsigned int u32;
typedef unsigned short u16;

__device__ __forceinline__ float sigf(float x) { return 1.0f / (1.0f + __expf(-x)); }
__device__ __forceinline__ float tanh_f(float x) { return 2.0f / (1.0f + __expf(-2.0f * x)) - 1.0f; }
__device__ __forceinline__ u16 f2bf(float f) {
  u32 u = __float_as_uint(f);
  return (u16)((u + 0x7fffu + ((u >> 16) & 1u)) >> 16);
}
__device__ __forceinline__ float bflo(u32 u) { return __uint_as_float(u << 16); }
__device__ __forceinline__ float bfhi(u32 u) { return __uint_as_float(u & 0xffff0000u); }

#if __has_builtin(__builtin_amdgcn_fdot2_f32_bf16)
#define HAVE_BF16_DOT2 1
typedef __bf16 bf16x2 __attribute__((ext_vector_type(2)));
__device__ __forceinline__ float dot2bf(u32 a, u32 b, float c) {
  return __builtin_amdgcn_fdot2_f32_bf16(__builtin_bit_cast(bf16x2, a),
                                         __builtin_bit_cast(bf16x2, b), c, false);
}
#else
#define HAVE_BF16_DOT2 0
#endif

// ---------------- prep: bf16 weight transposes/packs + combined biases ----------------
__global__ void prep_kernel(const float* __restrict__ wih0, const float* __restrict__ whh0,
                            const float* __restrict__ bih0, const float* __restrict__ bhh0,
                            const float* __restrict__ wih1, const float* __restrict__ whh1,
                            const float* __restrict__ bih1, const float* __restrict__ bhh1,
                            u16* __restrict__ wih0t, u16* __restrict__ wih1t,
                            u32* __restrict__ whh2_0, u32* __restrict__ whh2_1,
                            float* __restrict__ bias0, float* __restrict__ bias1) {
  int tid = blockIdx.x * blockDim.x + threadIdx.x;
  int nth = gridDim.x * blockDim.x;
  for (int idx = tid; idx < 2 * 256 * 1024; idx += nth) {
    int d = idx >> 18, rem = idx & 262143, e = rem >> 10, r = rem & 1023;
    wih0t[idx] = f2bf(wih0[(d * 1024 + r) * 256 + e]);
  }
  for (int idx = tid; idx < 2 * 512 * 1024; idx += nth) {
    int d = idx >> 19, rem = idx & 524287, e = rem >> 10, r = rem & 1023;
    wih1t[idx] = f2bf(wih1[(d * 1024 + r) * 512 + e]);
  }
  // whh2[d][k2][r] packs whh[d][r][2k2] (lo) and whh[d][r][2k2+1] (hi)
  for (int idx = tid; idx < 2 * 128 * 1024; idx += nth) {
    int d = idx >> 17, rem = idx & 131071, k2 = rem >> 10, r = rem & 1023;
    int base = (d * 1024 + r) * 256 + 2 * k2;
    whh2_0[idx] = (u32)f2bf(whh0[base]) | ((u32)f2bf(whh0[base + 1]) << 16);
    whh2_1[idx] = (u32)f2bf(whh1[base]) | ((u32)f2bf(whh1[base + 1]) << 16);
  }
  for (int idx = tid; idx < 2 * 1024; idx += nth) {
    bias0[idx] = bih0[idx] + bhh0[idx];
    bias1[idx] = bih1[idx] + bhh1[idx];
  }
}

// ---------------- input-projection GEMM: gx[dir][m][1024] = X[m] @ Wt[dir] + bias ----------------
template <int K, bool GATHER>
__global__ __launch_bounds__(256) void gemm_gx(
    const void* __restrict__ xsrc_v,
    const int* __restrict__ sent,
    const u16* __restrict__ wt,       // [2][K][1024] bf16
    const float* __restrict__ bias,   // [2][1024]
    u16* __restrict__ gx)             // [2*M][1024] bf16
{
  constexpr int BM = 64, BN = 64, BK = 32;
  __shared__ float Xs[BK][BM];
  __shared__ float Ws[BK][BN];
  const int tid = threadIdx.x;
  const int tx = tid & 15, ty = tid >> 4;
  const int n0 = blockIdx.x * BN;
  const int m0 = blockIdx.y * BM;
  const int dir = blockIdx.z;

  const int lrow = tid >> 3;
  const int lk = (tid & 7) * 4;
  const int wk = tid >> 3;
  const int wn = (tid & 7) * 8;

  float acc[4][4] = {};

  for (int k0 = 0; k0 < K; k0 += BK) {
#pragma unroll
    for (int rr = 0; rr < 2; ++rr) {
      int m = m0 + lrow + rr * 32;
      if constexpr (GATHER) {
        const float* xrow = (const float*)xsrc_v + (size_t)sent[m] * K;
        float4 v = *reinterpret_cast<const float4*>(xrow + k0 + lk);
        Xs[lk + 0][lrow + rr * 32] = v.x;
        Xs[lk + 1][lrow + rr * 32] = v.y;
        Xs[lk + 2][lrow + rr * 32] = v.z;
        Xs[lk + 3][lrow + rr * 32] = v.w;
      } else {
        const u16* xrow = (const u16*)xsrc_v + (size_t)m * K;
        uint2 v = *reinterpret_cast<const uint2*>(xrow + k0 + lk);
        Xs[lk + 0][lrow + rr * 32] = bflo(v.x);
        Xs[lk + 1][lrow + rr * 32] = bfhi(v.x);
        Xs[lk + 2][lrow + rr * 32] = bflo(v.y);
        Xs[lk + 3][lrow + rr * 32] = bfhi(v.y);
      }
    }
    {
      const u16* wp = wt + ((size_t)dir * K + k0 + wk) * 1024 + n0 + wn;
      uint4 wv = *reinterpret_cast<const uint4*>(wp);
      Ws[wk][wn + 0] = bflo(wv.x); Ws[wk][wn + 1] = bfhi(wv.x);
      Ws[wk][wn + 2] = bflo(wv.y); Ws[wk][wn + 3] = bfhi(wv.y);
      Ws[wk][wn + 4] = bflo(wv.z); Ws[wk][wn + 5] = bfhi(wv.z);
      Ws[wk][wn + 6] = bflo(wv.w); Ws[wk][wn + 7] = bfhi(wv.w);
    }
    __syncthreads();
#pragma unroll 8
    for (int k = 0; k < BK; ++k) {
      float4 a = *reinterpret_cast<const float4*>(&Xs[k][ty * 4]);
      float4 b = *reinterpret_cast<const float4*>(&Ws[k][tx * 4]);
      acc[0][0] += a.x * b.x; acc[0][1] += a.x * b.y; acc[0][2] += a.x * b.z; acc[0][3] += a.x * b.w;
      acc[1][0] += a.y * b.x; acc[1][1] += a.y * b.y; acc[1][2] += a.y * b.z; acc[1][3] += a.y * b.w;
      acc[2][0] += a.z * b.x; acc[2][1] += a.z * b.y; acc[2][2] += a.z * b.z; acc[2][3] += a.z * b.w;
      acc[3][0] += a.w * b.x; acc[3][1] += a.w * b.y; acc[3][2] += a.w * b.z; acc[3][3] += a.w * b.w;
    }
    __syncthreads();
  }

  float4 bv = *reinterpret_cast<const float4*>(&bias[dir * 1024 + n0 + tx * 4]);
#pragma unroll
  for (int i = 0; i < 4; ++i) {
    int m = m0 + ty * 4 + i;
    ushort4 sv;
    sv.x = f2bf(acc[i][0] + bv.x);
    sv.y = f2bf(acc[i][1] + bv.y);
    sv.z = f2bf(acc[i][2] + bv.z);
    sv.w = f2bf(acc[i][3] + bv.w);
    *reinterpret_cast<ushort4*>(gx + ((size_t)dir * Mn + m) * 1024 + n0 + tx * 4) = sv;
  }
}

// ---------------- sequential recurrence, 512 threads: k-split + LDS reduction ----------------
// Thread (kh, j): kh = tid>>8 handles k2 in [64*kh, 64*kh+64), j = tid&255 owns gate rows 4j..4j+3.
__global__ __launch_bounds__(512) void lstm_recur(
    const uint4* __restrict__ whh2,   // [2][128][256] uint4 (bf16 pairs, rows fastest)
    const u16* __restrict__ gx,       // [2*M][1024] bf16
    u16* __restrict__ out)            // [B][S][512] bf16
{
  __shared__ float4 gb[2][2][Hn];     // [kh][batch][j] partial gate pre-acts (16 KB)
#if HAVE_BF16_DOT2
  __shared__ u16 hb16[2][Hn];         // bf16 h per batch (packed pairs read as u32)
#else
  __shared__ float2 hb[Hn];           // fp32 h, interleaved batches
#endif
  const int tid = threadIdx.x;
  const int kh = tid >> 8;
  const int j = tid & 255;
  const int dir = blockIdx.x >> 5;
  const int b0 = (blockIdx.x & 31) * 2;

  float c0 = 0.0f, c1 = 0.0f;
#if HAVE_BF16_DOT2
  if (tid < 256) { hb16[0][j] = 0; hb16[1][j] = 0; }
#else
  if (tid < 256) hb[j] = make_float2(0.0f, 0.0f);
#endif
  __syncthreads();

  const uint4* wp = whh2 + (size_t)dir * 128 * 256 + (size_t)kh * 64 * 256 + j;

  for (int s = 0; s < Sn; ++s) {
    const int t = dir ? (Sn - 1 - s) : s;

    float4 a0, a1;
    if (kh == 0) {
      const u16* g0p = gx + ((size_t)(dir * Mn + b0 * Sn + t)) * 1024 + 4 * j;
      uint2 gu0 = *reinterpret_cast<const uint2*>(g0p);
      uint2 gu1 = *reinterpret_cast<const uint2*>(g0p + (size_t)Sn * 1024);
      a0 = make_float4(bflo(gu0.x), bfhi(gu0.x), bflo(gu0.y), bfhi(gu0.y));
      a1 = make_float4(bflo(gu1.x), bfhi(gu1.x), bflo(gu1.y), bfhi(gu1.y));
    } else {
      a0 = make_float4(0.f, 0.f, 0.f, 0.f);
      a1 = make_float4(0.f, 0.f, 0.f, 0.f);
    }

#if HAVE_BF16_DOT2
    const u32* hp0 = reinterpret_cast<const u32*>(&hb16[0][0]) + kh * 64;
    const u32* hp1 = reinterpret_cast<const u32*>(&hb16[1][0]) + kh * 64;
#pragma unroll 8
    for (int i = 0; i < 64; ++i) {
      uint4 w = wp[i * 256];
      u32 h0 = hp0[i];
      u32 h1 = hp1[i];
      a0.x = dot2bf(w.x, h0, a0.x); a1.x = dot2bf(w.x, h1, a1.x);
      a0.y = dot2bf(w.y, h0, a0.y); a1.y = dot2bf(w.y, h1, a1.y);
      a0.z = dot2bf(w.z, h0, a0.z); a1.z = dot2bf(w.z, h1, a1.z);
      a0.w = dot2bf(w.w, h0, a0.w); a1.w = dot2bf(w.w, h1, a1.w);
    }
#else
#pragma unroll 8
    for (int i = 0; i < 64; ++i) {
      uint4 w = wp[i * 256];
      float2 he = hb[2 * (kh * 64 + i)];
      float2 ho = hb[2 * (kh * 64 + i) + 1];
      float wl, wh;
      wl = bflo(w.x); wh = bfhi(w.x);
      a0.x += wl * he.x + wh * ho.x; a1.x += wl * he.y + wh * ho.y;
      wl = bflo(w.y); wh = bfhi(w.y);
      a0.y += wl * he.x + wh * ho.x; a1.y += wl * he.y + wh * ho.y;
      wl = bflo(w.z); wh = bfhi(w.z);
      a0.z += wl * he.x + wh * ho.x; a1.z += wl * he.y + wh * ho.y;
      wl = bflo(w.w); wh = bfhi(w.w);
      a0.w += wl * he.x + wh * ho.x; a1.w += wl * he.y + wh * ho.y;
    }
#endif
    gb[kh][0][j] = a0;
    gb[kh][1][j] = a1;
    __syncthreads();

    if (tid < 256) {
      const float* p00 = reinterpret_cast<const float*>(&gb[0][0][0]);
      const float* p10 = reinterpret_cast<const float*>(&gb[1][0][0]);
      const float* p01 = reinterpret_cast<const float*>(&gb[0][1][0]);
      const float* p11 = reinterpret_cast<const float*>(&gb[1][1][0]);
      float i0 = p00[j] + p10[j];
      float f0 = p00[Hn + j] + p10[Hn + j];
      float gg0 = p00[2 * Hn + j] + p10[2 * Hn + j];
      float o0 = p00[3 * Hn + j] + p10[3 * Hn + j];
      c0 = sigf(f0) * c0 + sigf(i0) * tanh_f(gg0);
      float h0 = sigf(o0) * tanh_f(c0);
      float i1 = p01[j] + p11[j];
      float f1 = p01[Hn + j] + p11[Hn + j];
      float gg1 = p01[2 * Hn + j] + p11[2 * Hn + j];
      float o1 = p01[3 * Hn + j] + p11[3 * Hn + j];
      c1 = sigf(f1) * c1 + sigf(i1) * tanh_f(gg1);
      float h1 = sigf(o1) * tanh_f(c1);
      u16 hb0 = f2bf(h0), hb1 = f2bf(h1);
#if HAVE_BF16_DOT2
      hb16[0][j] = hb0;
      hb16[1][j] = hb1;
#else
      hb[j] = make_float2(h0, h1);
#endif
      out[(size_t)(b0 * Sn + t) * HIDn + dir * Hn + j] = hb0;
      out[(size_t)((b0 + 1) * Sn + t) * HIDn + dir * Hn + j] = hb1;
    }
    __syncthreads();
  }
}

// ---------------- FC: one wave per (b,t), bf16 input rows ----------------
__global__ __launch_bounds__(64) void fc_kernel(const u16* __restrict__ out1,
                                                const float* __restrict__ fcw,
                                                const float* __restrict__ fcb,
                                                float* __restrict__ feats) {
  const int bs = blockIdx.x;
  const int l = threadIdx.x;
  const u16* row = out1 + (size_t)bs * HIDn;
  uint4 rv = *reinterpret_cast<const uint4*>(row + l * 8);
  float v[8];
  v[0] = bflo(rv.x); v[1] = bfhi(rv.x);
  v[2] = bflo(rv.y); v[3] = bfhi(rv.y);
  v[4] = bflo(rv.z); v[5] = bfhi(rv.z);
  v[6] = bflo(rv.w); v[7] = bfhi(rv.w);
#pragma unroll
  for (int tag = 0; tag < Tn; ++tag) {
    const float* w = fcw + tag * HIDn + l * 8;
    float4 w0 = *reinterpret_cast<const float4*>(w);
    float4 w1 = *reinterpret_cast<const float4*>(w + 4);
    float acc = v[0] * w0.x + v[1] * w0.y + v[2] * w0.z + v[3] * w0.w
              + v[4] * w1.x + v[5] * w1.y + v[6] * w1.z + v[7] * w1.w;
#pragma unroll
    for (int off = 32; off; off >>= 1) acc += __shfl_xor(acc, off);
    if (l == 0) feats[bs * Tn + tag] = acc + fcb[tag];
  }
}

// ---------------- CRF forward + gold, one wave per batch ----------------
__global__ __launch_bounds__(64) void crf_kernel(const float* __restrict__ feats,
                                                 const int* __restrict__ tags,
                                                 const int* __restrict__ lens,
                                                 const float* __restrict__ trans,
                                                 float* __restrict__ scores) {
  const int b = blockIdx.x;
  const int j = threadIdx.x;
  const int jj = j < Tn ? j : Tn - 1;
  const int len = lens[b];

  float trc[Tn];
#pragma unroll
  for (int i = 0; i < Tn; ++i) trc[i] = trans[i * Tn + jj];
  const float trS = trans[jj * Tn + STOP_T];

  float alpha = (j == START_T) ? 0.0f : NEGV;
  const float* fb = feats + (size_t)b * Sn * Tn;

  for (int t = 0; t < Sn; ++t) {
    float f = (j < Tn) ? fb[t * Tn + j] : 0.0f;
    float v[Tn];
    float m = -3.0e38f;
#pragma unroll
    for (int i = 0; i < Tn; ++i) {
      float ai = __shfl(alpha, i);
      v[i] = ai + trc[i];
      m = fmaxf(m, v[i]);
    }
    float ssum = 0.0f;
#pragma unroll
    for (int i = 0; i < Tn; ++i) ssum += __expf(v[i] - m);
    float newa = m + __logf(ssum) + f;
    if (t < len && j < Tn) alpha = newa;
  }

  float val = (j < Tn) ? alpha + trS : -3.0e38f;
  float m = val;
#pragma unroll
  for (int off = 32; off; off >>= 1) m = fmaxf(m, __shfl_xor(m, off));
  float se = (j < Tn) ? __expf(val - m) : 0.0f;
#pragma unroll
  for (int off = 32; off; off >>= 1) se += __shfl_xor(se, off);
  float fscore = m + __logf(se);

  const int* tg = tags + b * Sn;
  float part = 0.0f;
  for (int q = 0; q < 8; ++q) {
    int s0 = j * 8 + q;
    if (s0 < Sn - 1 && (s0 + 1) < len) {
      int ta = tg[s0], tb = tg[s0 + 1];
      part += trans[ta * Tn + tb] + fb[s0 * Tn + tb];
    }
  }
#pragma unroll
  for (int off = 32; off; off >>= 1) part += __shfl_xor(part, off);

  if (j == 0) {
    int t0 = tg[0];
    int tl = tg[len - 1];
    float gold = trans[START_T * Tn + t0] + fb[0 * Tn + t0] + part + trans[tl * Tn + STOP_T];
    scores[b] = fscore - gold;
  }
}

__global__ void finalize_kernel(const float* __restrict__ scores, float* __restrict__ out) {
  int l = threadIdx.x;
  float v = scores[l];
#pragma unroll
  for (int off = 32; off; off >>= 1) v += __shfl_xor(v, off);
  if (l == 0) out[0] = v / 64.0f;
}

extern "C" void kernel_launch(void* const* d_in, const int* in_sizes, int n_in,
                              void* d_out, int out_size, void* d_ws, size_t ws_size,
                              hipStream_t stream) {
  const int* sent = (const int*)d_in[0];
  const int* tags = (const int*)d_in[1];
  const int* lens = (const int*)d_in[2];
  const float* emb = (const float*)d_in[3];
  const float* wih0 = (const float*)d_in[4];
  const float* whh0 = (const float*)d_in[5];
  const float* bih0 = (const float*)d_in[6];
  const float* bhh0 = (const float*)d_in[7];
  const float* wih1 = (const float*)d_in[8];
  const float* whh1 = (const float*)d_in[9];
  const float* bih1 = (const float*)d_in[10];
  const float* bhh1 = (const float*)d_in[11];
  const float* fcw = (const float*)d_in[12];
  const float* fcb = (const float*)d_in[13];
  const float* trans = (const float*)d_in[14];

  // workspace layout (~168 MB total)
  char* ws = (char*)d_ws;
  u16* outb = (u16*)ws;                                  // Mn*512 bf16 = 33,554,432 B
  u16* gx = (u16*)(ws + 33554432);                       // 2*Mn*1024 bf16 = 134,217,728 B
  float* feats = (float*)(ws + 33554432 + 134217728);    // Mn*9 fp32
  float* scores = feats + (size_t)Mn * Tn;               // 64
  float* bias0 = scores + 64;                            // 2048
  float* bias1 = bias0 + 2048;                           // 2048
  u16* wih0t = (u16*)(bias1 + 2048);                     // 524,288 u16
  u16* wih1t = wih0t + 2 * 256 * 1024;                   // 1,048,576 u16
  u32* whh2_0 = (u32*)(wih1t + 2 * 512 * 1024);          // 262,144 u32
  u32* whh2_1 = whh2_0 + 2 * 128 * 1024;                 // 262,144 u32

  prep_kernel<<<2048, 256, 0, stream>>>(wih0, whh0, bih0, bhh0, wih1, whh1, bih1, bhh1,
                                        wih0t, wih1t, whh2_0, whh2_1, bias0, bias1);

  dim3 ggrid(1024 / 64, Mn / 64, 2);
  gemm_gx<256, true><<<ggrid, 256, 0, stream>>>(emb, sent, wih0t, bias0, gx);
  lstm_recur<<<64, 512, 0, stream>>>((const uint4*)whh2_0, gx, outb);
  gemm_gx<512, false><<<ggrid, 256, 0, stream>>>(outb, nullptr, wih1t, bias1, gx);
  lstm_recur<<<64, 512, 0, stream>>>((const uint4*)whh2_1, gx, outb);

  fc_kernel<<<Mn, 64, 0, stream>>>(outb, fcw, fcb, feats);
  crf_kernel<<<Bn, 64, 0, stream>>>(feats, tags, lens, trans, scores);
  finalize_kernel<<<1, 64, 0, stream>>>(scores, (float*)d_out);
}